// Round 7
// baseline (285.853 us; speedup 1.0000x reference)
//
#include <hip/hip_runtime.h>
#include <hip/hip_bf16.h>

#define B_  16
#define C_  256
#define H_  48
#define W_  64
#define ND  21           // displacements per axis
#define HW  (H_ * W_)
#define CHW (C_ * H_ * W_)

typedef __attribute__((ext_vector_type(8))) short bf16x8;
typedef __attribute__((ext_vector_type(4))) float f32x4;

__device__ __forceinline__ unsigned int bf16rtne(float f) {
  unsigned int u = __builtin_bit_cast(unsigned int, f);
  return (u + 0x7fffu + ((u >> 16) & 1u)) >> 16;
}

// ---------------------------------------------------------------------------
// Kernel 1 v2 (unchanged): fp32 NCHW -> bf16 FRAGMENT-MAJOR, 2 channel-half
// blocks per (input,b,y) row. grid = 4*B*H = 3072.
//   granule G = ks*256 + t16*64 + quad*16 + l15  (16B granules)
//   content  = bf16 src[x = t16*16+l15][k = ks*32+quad*8 .. +8)
// ---------------------------------------------------------------------------
__global__ __launch_bounds__(256, 8) void transpose_cvt(
    const float* __restrict__ in1, const float* __restrict__ in2,
    unsigned short* __restrict__ o1, unsigned short* __restrict__ o2) {
  __shared__ unsigned short T[128 * 66];   // [cl][x], stride 66 (odd word stride)

  int bid = blockIdx.x;
  int ch  = bid & 1;                       // channel half: c in [ch*128, ch*128+128)
  int blk = bid >> 1;
  const float* in = in1;
  unsigned short* op = o1;
  if (blk >= B_ * H_) { blk -= B_ * H_; in = in2; op = o2; }
  int y = blk % H_;
  int b = blk / H_;
  int t = threadIdx.x;

  // ---- phase 1: global fp32 -> bf16 -> LDS[cl][x] ----
  int u  = t & 15;          // x-quad: x = 4u..4u+3
  int cb = t >> 4;          // local c base 0..15, cl = cb + 16r
  const float* src = in + (long)b * CHW + (long)(ch * 128) * HW + y * W_ + u * 4;
#pragma unroll
  for (int r = 0; r < 8; r++) {
    int cl = cb + 16 * r;
    float4 v = *(const float4*)(src + (long)cl * HW);
    unsigned int p0 = bf16rtne(v.x) | (bf16rtne(v.y) << 16);
    unsigned int p1 = bf16rtne(v.z) | (bf16rtne(v.w) << 16);
    unsigned int* Tw = (unsigned int*)(T + cl * 66 + u * 4);
    Tw[0] = p0;
    Tw[1] = p1;
  }
  __syncthreads();

  // ---- phase 2: LDS gather -> fragment-major 16B stores ----
  int x   = t >> 2;         // pixel 0..63
  int cq  = t & 3;
  int t16 = x >> 4, xl = x & 15;
  unsigned short* orow = op + (long)(b * H_ + y) * (W_ * C_);
#pragma unroll
  for (int g = 0; g < 4; g++) {
    int gg = (g + cq) & 3;              // bank-spread rotation
    int kgl = cq * 4 + gg;              // local k-granule 0..15
    int c0 = kgl * 8;                   // first local channel of this granule
    unsigned int wv[4];
#pragma unroll
    for (int k2 = 0; k2 < 4; k2++) {
      unsigned int lo = T[(c0 + 2 * k2) * 66 + x];
      unsigned int hi = T[(c0 + 2 * k2 + 1) * 66 + x];
      wv[k2] = lo | (hi << 16);
    }
    int kg = ch * 16 + kgl;             // global k-granule 0..31
    int ks = kg >> 2, qd = kg & 3;
    int G = ks * 256 + t16 * 64 + qd * 16 + xl;
    *(uint4*)(orow + (long)G * 8) = *(uint4*)wv;
  }
}

// ---------------------------------------------------------------------------
// async global -> LDS, 16B per lane (wave-uniform LDS base + lane*16)
// ---------------------------------------------------------------------------
__device__ __forceinline__ void gl_lds16(const void* g, void* l) {
  __builtin_amdgcn_global_load_lds(
      (const __attribute__((address_space(1))) void*)g,
      (__attribute__((address_space(3))) void*)l, 16, 0, 0);
}

// ---------------------------------------------------------------------------
// Kernel 2: correlation v12 — v11's traffic plan, v10's schedule discipline.
// Ledger: v10 (52us) = aggregate-L2-BW wall (1.6GB -> ~31 TB/s ~= ceiling).
// v11 (132us) = right traffic plan, broken schedule: bp[8] (32 VGPR) held
// live across the store phase in a 76-VGPR kernel -> spill pathology
// (VALUBusy 54%), plus per-MFMA ds_read chains.
// v12:
//   - A row (32KB frag-major) in LDS, staged once (identity gl_lds16 copy).
//   - waves n-split (wave w owns ntile w): B = 32KB/block-iter, 0 redundancy.
//     L2 traffic 1.6GB -> 0.4GB (~8 TB/s, off the ceiling).
//   - ks-loop software-pipelined at distance 1: loads (B global, A ds_read)
//     for ks+1 issue before MFMAs of ks. Rotating regs: a_cur[4]+a_nxt[4]+
//     b_cur+b_nxt+acc[4] ~= 60 VGPR peak; only ONE b (4 VGPR) + a_cur (16)
//     cross the store phase. No spill pressure.
//   - keeps: XCD swizzle, double-buffered slab, coalesced stores,
//     lgkmcnt-only in-loop barrier.
// LDS = 32KB A + 10.9KB slab = 43.7KB -> 3 blocks/CU, grid fully resident.
// ---------------------------------------------------------------------------
__global__ __launch_bounds__(256, 3) void corr_kernel(
    const unsigned short* __restrict__ A2, const unsigned short* __restrict__ B2,
    float* __restrict__ out) {
  __shared__ unsigned short Alds[16384];    // 32KB A row, fragment-major
  __shared__ float slab[2][ND * 65];        // [buf][dxi][x], pad 65

  int bid = blockIdx.x;
  int blk = (bid & 7) * 96 + (bid >> 3);    // XCD swizzle, bijective (768=8*96)
  int y    = blk % H_;
  int b    = blk / H_;
  int t    = threadIdx.x;
  int lane = t & 63;
  int w    = t >> 6;                        // wave = n-tile index 0..3
  int l15  = lane & 15;
  int quad = lane >> 4;

  // contiguous valid-dyi range: y2 = y + 2*d - 20 in [0,H)
  int dlo = (y < 20) ? ((21 - y) >> 1) : 0;
  int dhi = (67 - y) >> 1; if (dhi > 20) dhi = 20;

  // ---- prologue: stage A row into LDS (identity copy, 32 x 1KB chunks) ----
  const unsigned short* rowA = A2 + (long)(b * H_ + y) * (W_ * C_);
  {
    const unsigned short* srcA = rowA + lane * 8;
#pragma unroll
    for (int j = 0; j < 8; j++) {
      int c = w * 8 + j;                    // chunk 0..31 (1KB each)
      gl_lds16(srcA + c * 512, &Alds[c * 512]);
    }
  }

  // ---- per-lane slab-scatter offsets (dyi-invariant): dxi*65 + xx, or -1 ----
  // wave w owns ntile w: xp = w*16 + l15; m-tile m: xx = m*16 + quad*4 + r
  int soff[4][4];
  bool live[4];
#pragma unroll
  for (int m = 0; m < 4; m++) {
    int diff = w - m;
    live[m] = (diff >= -2 && diff <= 2);
#pragma unroll
    for (int r = 0; r < 4; r++) {
      int xx = m * 16 + quad * 4 + r;
      int xp = w * 16 + l15;
      int dx = xp - xx;
      soff[m][r] =
          (dx >= -20 && dx <= 20 && !(dx & 1)) ? (((dx + 20) >> 1) * 65 + xx) : -1;
    }
  }

  float* ob = out + (long)b * (ND * ND * HW) + y * W_;

  // ---- zero planes for out-of-range dyi (overlaps A-stage latency) ----
  for (int d = 0; d < dlo; d++) {
    float* od = ob + (long)d * (ND * HW);
    for (int i = t; i < ND * W_; i += 256) od[(i >> 6) * HW + (i & 63)] = 0.0f;
  }
  for (int d = dhi + 1; d < ND; d++) {
    float* od = ob + (long)d * (ND * HW);
    for (int i = t; i < ND * W_; i += 256) od[(i >> 6) * HW + (i & 63)] = 0.0f;
  }

  // ---- zero-init both slabs (contiguous) ----
  {
    float* s0 = &slab[0][0];
    for (int i = t; i < 2 * ND * 65; i += 256) s0[i] = 0.0f;
  }
  __syncthreads();   // full barrier: drains A-stage vmcnt + slab init

  const unsigned short* browbase = B2 + (long)(b * H_) * (W_ * C_);
  int sp = 0;
  for (int d = dlo; d <= dhi; d++) {
    int y2 = y + 2 * d - 20;
    const unsigned short* rb =
        browbase + (long)y2 * (W_ * C_) + w * 512 + lane * 8;  // this wave's ntile

    // ---- (0) preload ks=0 only: 1 B-load (4 VGPR) + A frags from LDS ----
    bf16x8 b_cur = *(const bf16x8*)(rb);
    bf16x8 a_cur[4];
#pragma unroll
    for (int m = 0; m < 4; m++)
      if (live[m])
        a_cur[m] = *(const bf16x8*)(&Alds[m * 512 + lane * 8]);

    // ---- (1) store previous dyi's slab (coalesced 256B/wave) + rezero ----
    if (d > dlo) {
      float* odp = ob + (long)(d - 1) * (ND * HW);
      float* sl = slab[sp ^ 1];
      for (int i = t; i < ND * W_; i += 256) {
        int dxi = i >> 6, x = i & 63;
        odp[dxi * HW + x] = sl[dxi * 65 + x];
        sl[dxi * 65 + x] = 0.0f;
      }
    }

    // ---- (2) MFMA loop, distance-1 software pipeline ----
    f32x4 acc[4];
#pragma unroll
    for (int m = 0; m < 4; m++) acc[m] = (f32x4){0.f, 0.f, 0.f, 0.f};

#pragma unroll
    for (int ks = 0; ks < 8; ks++) {
      bf16x8 b_nxt;
      bf16x8 a_nxt[4];
      if (ks < 7) {
        b_nxt = *(const bf16x8*)(rb + (ks + 1) * 2048);
#pragma unroll
        for (int m = 0; m < 4; m++)
          if (live[m])
            a_nxt[m] = *(const bf16x8*)(&Alds[(ks + 1) * 2048 + m * 512 + lane * 8]);
      }
#pragma unroll
      for (int m = 0; m < 4; m++)
        if (live[m])
          acc[m] = __builtin_amdgcn_mfma_f32_16x16x32_bf16(a_cur[m], b_cur, acc[m],
                                                           0, 0, 0);
      if (ks < 7) {
        b_cur = b_nxt;
#pragma unroll
        for (int m = 0; m < 4; m++)
          if (live[m]) a_cur[m] = a_nxt[m];
      }
    }

    // ---- (3) band-extract scatter into slab[sp] ----
#pragma unroll
    for (int m = 0; m < 4; m++)
      if (live[m]) {
#pragma unroll
        for (int r = 0; r < 4; r++) {
          int so = soff[m][r];
          if (so >= 0) slab[sp][so] = acc[m][r] * (1.0f / 256.0f);
        }
      }

    // ---- (4) relaxed barrier: LDS drained, NO vmcnt drain ----
    asm volatile("s_waitcnt lgkmcnt(0)" ::: "memory");
    __builtin_amdgcn_s_barrier();
    __builtin_amdgcn_sched_barrier(0);
    sp ^= 1;
  }

  // ---- epilogue: store last dyi's slab ----
  {
    float* odp = ob + (long)dhi * (ND * HW);
    float* sl = slab[sp ^ 1];
    for (int i = t; i < ND * W_; i += 256) {
      int dxi = i >> 6, x = i & 63;
      odp[dxi * HW + x] = sl[dxi * 65 + x];
    }
  }
}

// ---------------------------------------------------------------------------
extern "C" void kernel_launch(void* const* d_in, const int* in_sizes, int n_in,
                              void* d_out, int out_size, void* d_ws, size_t ws_size,
                              hipStream_t stream) {
  (void)in_sizes; (void)n_in; (void)out_size; (void)ws_size;
  const float* in1 = (const float*)d_in[0];
  const float* in2 = (const float*)d_in[1];
  float* out = (float*)d_out;

  unsigned short* o1 = (unsigned short*)d_ws;                    // bf16 frag-major
  unsigned short* o2 = o1 + (size_t)B_ * H_ * W_ * C_;           // bf16 frag-major

  transpose_cvt<<<4 * B_ * H_, 256, 0, stream>>>(in1, in2, o1, o2);
  corr_kernel<<<B_ * H_, 256, 0, stream>>>(o1, o2, out);
}

// Round 8
// 206.471 us; speedup vs baseline: 1.3845x; 1.3845x over previous
//
#include <hip/hip_runtime.h>
#include <hip/hip_bf16.h>

#define B_  16
#define C_  256
#define H_  48
#define W_  64
#define ND  21           // displacements per axis
#define HW  (H_ * W_)
#define CHW (C_ * H_ * W_)

typedef __attribute__((ext_vector_type(8))) short bf16x8;
typedef __attribute__((ext_vector_type(4))) float f32x4;

__device__ __forceinline__ unsigned int bf16rtne(float f) {
  unsigned int u = __builtin_bit_cast(unsigned int, f);
  return (u + 0x7fffu + ((u >> 16) & 1u)) >> 16;
}

// ---------------------------------------------------------------------------
// Kernel 1 v2 (unchanged): fp32 NCHW -> bf16 FRAGMENT-MAJOR, 2 channel-half
// blocks per (input,b,y) row. grid = 4*B*H = 3072.
//   granule G = ks*256 + t16*64 + quad*16 + l15  (16B granules)
//   content  = bf16 src[x = t16*16+l15][k = ks*32+quad*8 .. +8)
// ---------------------------------------------------------------------------
__global__ __launch_bounds__(256, 8) void transpose_cvt(
    const float* __restrict__ in1, const float* __restrict__ in2,
    unsigned short* __restrict__ o1, unsigned short* __restrict__ o2) {
  __shared__ unsigned short T[128 * 66];   // [cl][x], stride 66 (odd word stride)

  int bid = blockIdx.x;
  int ch  = bid & 1;                       // channel half: c in [ch*128, ch*128+128)
  int blk = bid >> 1;
  const float* in = in1;
  unsigned short* op = o1;
  if (blk >= B_ * H_) { blk -= B_ * H_; in = in2; op = o2; }
  int y = blk % H_;
  int b = blk / H_;
  int t = threadIdx.x;

  // ---- phase 1: global fp32 -> bf16 -> LDS[cl][x] ----
  int u  = t & 15;          // x-quad: x = 4u..4u+3
  int cb = t >> 4;          // local c base 0..15, cl = cb + 16r
  const float* src = in + (long)b * CHW + (long)(ch * 128) * HW + y * W_ + u * 4;
#pragma unroll
  for (int r = 0; r < 8; r++) {
    int cl = cb + 16 * r;
    float4 v = *(const float4*)(src + (long)cl * HW);
    unsigned int p0 = bf16rtne(v.x) | (bf16rtne(v.y) << 16);
    unsigned int p1 = bf16rtne(v.z) | (bf16rtne(v.w) << 16);
    unsigned int* Tw = (unsigned int*)(T + cl * 66 + u * 4);
    Tw[0] = p0;
    Tw[1] = p1;
  }
  __syncthreads();

  // ---- phase 2: LDS gather -> fragment-major 16B stores ----
  int x   = t >> 2;         // pixel 0..63
  int cq  = t & 3;
  int t16 = x >> 4, xl = x & 15;
  unsigned short* orow = op + (long)(b * H_ + y) * (W_ * C_);
#pragma unroll
  for (int g = 0; g < 4; g++) {
    int gg = (g + cq) & 3;              // bank-spread rotation
    int kgl = cq * 4 + gg;              // local k-granule 0..15
    int c0 = kgl * 8;                   // first local channel of this granule
    unsigned int wv[4];
#pragma unroll
    for (int k2 = 0; k2 < 4; k2++) {
      unsigned int lo = T[(c0 + 2 * k2) * 66 + x];
      unsigned int hi = T[(c0 + 2 * k2 + 1) * 66 + x];
      wv[k2] = lo | (hi << 16);
    }
    int kg = ch * 16 + kgl;             // global k-granule 0..31
    int ks = kg >> 2, qd = kg & 3;
    int G = ks * 256 + t16 * 64 + qd * 16 + xl;
    *(uint4*)(orow + (long)G * 8) = *(uint4*)wv;
  }
}

// ---------------------------------------------------------------------------
// async global -> LDS, 16B per lane (wave-uniform LDS base + lane*16)
// ---------------------------------------------------------------------------
__device__ __forceinline__ void gl_lds16(const void* g, void* l) {
  __builtin_amdgcn_global_load_lds(
      (const __attribute__((address_space(1))) void*)g,
      (__attribute__((address_space(3))) void*)l, 16, 0, 0);
}

// ---------------------------------------------------------------------------
// Kernel 2: correlation v13 — v10's EXACT structure, A-frags from LDS.
// Ledger: v10 (52.4us) = L2-BW wall: 128KB/block-iter (A remat 2x + B 2x)
// = 1.61GB -> 31 TB/s ~= the 34.5 TB/s L2 ceiling. v11/v12 (132/139us)
// regressed via CONDITIONAL register rotation (`if(live) a_cur=a_nxt` with
// vector cond -> v_cndmask chains + exec juggling, VALUBusy 54-61%) and a
// worse A-sharing partition (n-split: 1 MFMA/A-frag vs mh-nh's 2).
// v13 changes ONE thing vs v10: afrag source = LDS (staged once per block,
// identity gl_lds16 copy). Loop body keeps v10's unconditional SSA rotation.
//   per ks: 2 ds_read_b128 (A, base+imm) + 2 global B + 4 live-guarded MFMA.
//   L2 traffic halves (B only, 0.81GB); A moves to LDS (128 B/cyc/CU).
// LDS = 32KB A + 10.9KB slab = 43.7KB -> 3 blocks/CU, grid fully resident.
// ---------------------------------------------------------------------------
__global__ __launch_bounds__(256, 3) void corr_kernel(
    const unsigned short* __restrict__ A2, const unsigned short* __restrict__ B2,
    float* __restrict__ out) {
  __shared__ unsigned short Alds[16384];    // 32KB A row, fragment-major
  __shared__ float slab[2][ND * 65];        // [buf][dxi][x], pad 65

  int bid = blockIdx.x;
  int blk = (bid & 7) * 96 + (bid >> 3);    // XCD swizzle, bijective (768=8*96)
  int y    = blk % H_;
  int b    = blk / H_;
  int t    = threadIdx.x;
  int lane = t & 63;
  int w    = t >> 6;
  int l15  = lane & 15;
  int quad = lane >> 4;
  int mh   = w & 1;
  int nh   = w >> 1;

  // contiguous valid-dyi range: y2 = y + 2*d - 20 in [0,H)
  int dlo = (y < 20) ? ((21 - y) >> 1) : 0;
  int dhi = (67 - y) >> 1; if (dhi > 20) dhi = 20;

  // ---- prologue: stage A row into LDS (identity copy, 32 x 1KB chunks) ----
  const unsigned short* rowA = A2 + (long)(b * H_ + y) * (W_ * C_);
  {
    const unsigned short* srcA = rowA + lane * 8;
#pragma unroll
    for (int j = 0; j < 8; j++) {
      int c = w * 8 + j;                    // chunk 0..31 (1KB each)
      gl_lds16(srcA + c * 512, &Alds[c * 512]);
    }
  }

  // ---- per-lane slab-scatter offsets (dyi-invariant): dxi*65 + xx, or -1 ----
  int soff[2][2][4];
#pragma unroll
  for (int mtl = 0; mtl < 2; mtl++)
#pragma unroll
    for (int ntl = 0; ntl < 2; ntl++)
#pragma unroll
      for (int r = 0; r < 4; r++) {
        int xx = (mh * 2 + mtl) * 16 + quad * 4 + r;
        int xp = (nh * 2 + ntl) * 16 + l15;
        int dx = xp - xx;
        soff[mtl][ntl][r] =
            (dx >= -20 && dx <= 20 && !(dx & 1)) ? (((dx + 20) >> 1) * 65 + xx) : -1;
      }

  // tile-pair liveness (wave-uniform): |16*(ntg-mtg)| <= 35
  bool live[2][2];
#pragma unroll
  for (int mtl = 0; mtl < 2; mtl++)
#pragma unroll
    for (int ntl = 0; ntl < 2; ntl++) {
      int diff = (nh * 2 + ntl) - (mh * 2 + mtl);
      live[mtl][ntl] = (diff >= -2 && diff <= 2);
    }

  float* ob = out + (long)b * (ND * ND * HW) + y * W_;

  // ---- zero planes for out-of-range dyi (overlaps A-stage latency) ----
  for (int d = 0; d < dlo; d++) {
    float* od = ob + (long)d * (ND * HW);
    for (int i = t; i < ND * W_; i += 256) od[(i >> 6) * HW + (i & 63)] = 0.0f;
  }
  for (int d = dhi + 1; d < ND; d++) {
    float* od = ob + (long)d * (ND * HW);
    for (int i = t; i < ND * W_; i += 256) od[(i >> 6) * HW + (i & 63)] = 0.0f;
  }

  // ---- zero-init both slabs (contiguous) ----
  {
    float* s0 = &slab[0][0];
    for (int i = t; i < 2 * ND * 65; i += 256) s0[i] = 0.0f;
  }
  __syncthreads();   // full barrier: drains A-stage vmcnt + slab init

  // LDS byte bases for this wave's two A m-tiles (dyi-invariant)
  const unsigned short* aBase0 = &Alds[(mh * 2 + 0) * 512 + lane * 8];
  const unsigned short* aBase1 = &Alds[(mh * 2 + 1) * 512 + lane * 8];

  const unsigned short* browbase = B2 + (long)(b * H_) * (W_ * C_);
  int sp = 0;
  for (int d = dlo; d <= dhi; d++) {
    int y2 = y + 2 * d - 20;
    const unsigned short* rowB = browbase + (long)y2 * (W_ * C_);
    const unsigned short* rb0 = rowB + (nh * 2 + 0) * 512 + lane * 8;
    const unsigned short* rb1 = rowB + (nh * 2 + 1) * 512 + lane * 8;

    // ---- (0) preload ks=0: 2 global B + 2 LDS A (store phase covers lat) ----
    bf16x8 bc0 = *(const bf16x8*)(rb0);
    bf16x8 bc1 = *(const bf16x8*)(rb1);
    bf16x8 a0  = *(const bf16x8*)(aBase0);
    bf16x8 a1  = *(const bf16x8*)(aBase1);

    // ---- (1) store previous dyi's slab (coalesced 256B/wave) + rezero ----
    if (d > dlo) {
      float* odp = ob + (long)(d - 1) * (ND * HW);
      float* sl = slab[sp ^ 1];
      for (int i = t; i < ND * W_; i += 256) {
        int dxi = i >> 6, x = i & 63;
        odp[dxi * HW + x] = sl[dxi * 65 + x];
        sl[dxi * 65 + x] = 0.0f;
      }
    }

    // ---- (2) MFMA loop: depth-1 UNCONDITIONAL SSA rotation (v10 shape) ----
    f32x4 acc[2][2];
#pragma unroll
    for (int mtl = 0; mtl < 2; mtl++)
#pragma unroll
      for (int ntl = 0; ntl < 2; ntl++) acc[mtl][ntl] = (f32x4){0.f, 0.f, 0.f, 0.f};

#pragma unroll
    for (int ks = 0; ks < 8; ks++) {
      int ksn = (ks < 7) ? ks + 1 : 0;               // clamp: no OOB read
      bf16x8 bn0 = *(const bf16x8*)(rb0 + ksn * 2048);
      bf16x8 bn1 = *(const bf16x8*)(rb1 + ksn * 2048);
      bf16x8 an0 = *(const bf16x8*)(aBase0 + ksn * 2048);
      bf16x8 an1 = *(const bf16x8*)(aBase1 + ksn * 2048);
      if (live[0][0])
        acc[0][0] = __builtin_amdgcn_mfma_f32_16x16x32_bf16(a0, bc0, acc[0][0], 0, 0, 0);
      if (live[0][1])
        acc[0][1] = __builtin_amdgcn_mfma_f32_16x16x32_bf16(a0, bc1, acc[0][1], 0, 0, 0);
      if (live[1][0])
        acc[1][0] = __builtin_amdgcn_mfma_f32_16x16x32_bf16(a1, bc0, acc[1][0], 0, 0, 0);
      if (live[1][1])
        acc[1][1] = __builtin_amdgcn_mfma_f32_16x16x32_bf16(a1, bc1, acc[1][1], 0, 0, 0);
      bc0 = bn0; bc1 = bn1; a0 = an0; a1 = an1;      // unconditional rotation
    }

    // ---- (3) band-extract scatter into slab[sp] ----
#pragma unroll
    for (int mtl = 0; mtl < 2; mtl++)
#pragma unroll
      for (int ntl = 0; ntl < 2; ntl++)
#pragma unroll
        for (int r = 0; r < 4; r++) {
          int so = soff[mtl][ntl][r];
          if (so >= 0) slab[sp][so] = acc[mtl][ntl][r] * (1.0f / 256.0f);
        }

    // ---- (4) relaxed barrier: LDS drained, NO vmcnt drain ----
    asm volatile("s_waitcnt lgkmcnt(0)" ::: "memory");
    __builtin_amdgcn_s_barrier();
    __builtin_amdgcn_sched_barrier(0);
    sp ^= 1;
  }

  // ---- epilogue: store last dyi's slab ----
  {
    float* odp = ob + (long)dhi * (ND * HW);
    float* sl = slab[sp ^ 1];
    for (int i = t; i < ND * W_; i += 256) {
      int dxi = i >> 6, x = i & 63;
      odp[dxi * HW + x] = sl[dxi * 65 + x];
    }
  }
}

// ---------------------------------------------------------------------------
extern "C" void kernel_launch(void* const* d_in, const int* in_sizes, int n_in,
                              void* d_out, int out_size, void* d_ws, size_t ws_size,
                              hipStream_t stream) {
  (void)in_sizes; (void)n_in; (void)out_size; (void)ws_size;
  const float* in1 = (const float*)d_in[0];
  const float* in2 = (const float*)d_in[1];
  float* out = (float*)d_out;

  unsigned short* o1 = (unsigned short*)d_ws;                    // bf16 frag-major
  unsigned short* o2 = o1 + (size_t)B_ * H_ * W_ * C_;           // bf16 frag-major

  transpose_cvt<<<4 * B_ * H_, 256, 0, stream>>>(in1, in2, o1, o2);
  corr_kernel<<<B_ * H_, 256, 0, stream>>>(o1, o2, out);
}

// Round 9
// 205.306 us; speedup vs baseline: 1.3923x; 1.0057x over previous
//
#include <hip/hip_runtime.h>
#include <hip/hip_bf16.h>

#define B_  16
#define C_  256
#define H_  48
#define W_  64
#define ND  21           // displacements per axis
#define HW  (H_ * W_)
#define CHW (C_ * H_ * W_)

typedef __attribute__((ext_vector_type(8))) short bf16x8;
typedef __attribute__((ext_vector_type(4))) float f32x4;

__device__ __forceinline__ unsigned int bf16rtne(float f) {
  unsigned int u = __builtin_bit_cast(unsigned int, f);
  return (u + 0x7fffu + ((u >> 16) & 1u)) >> 16;
}

// ---------------------------------------------------------------------------
// Kernel 1 v2 (unchanged): fp32 NCHW -> bf16 FRAGMENT-MAJOR, 2 channel-half
// blocks per (input,b,y) row. grid = 4*B*H = 3072.
//   granule G = ks*256 + t16*64 + quad*16 + l15  (16B granules)
//   content  = bf16 src[x = t16*16+l15][k = ks*32+quad*8 .. +8)
// ---------------------------------------------------------------------------
__global__ __launch_bounds__(256, 8) void transpose_cvt(
    const float* __restrict__ in1, const float* __restrict__ in2,
    unsigned short* __restrict__ o1, unsigned short* __restrict__ o2) {
  __shared__ unsigned short T[128 * 66];   // [cl][x], stride 66 (odd word stride)

  int bid = blockIdx.x;
  int ch  = bid & 1;                       // channel half: c in [ch*128, ch*128+128)
  int blk = bid >> 1;
  const float* in = in1;
  unsigned short* op = o1;
  if (blk >= B_ * H_) { blk -= B_ * H_; in = in2; op = o2; }
  int y = blk % H_;
  int b = blk / H_;
  int t = threadIdx.x;

  // ---- phase 1: global fp32 -> bf16 -> LDS[cl][x] ----
  int u  = t & 15;          // x-quad: x = 4u..4u+3
  int cb = t >> 4;          // local c base 0..15, cl = cb + 16r
  const float* src = in + (long)b * CHW + (long)(ch * 128) * HW + y * W_ + u * 4;
#pragma unroll
  for (int r = 0; r < 8; r++) {
    int cl = cb + 16 * r;
    float4 v = *(const float4*)(src + (long)cl * HW);
    unsigned int p0 = bf16rtne(v.x) | (bf16rtne(v.y) << 16);
    unsigned int p1 = bf16rtne(v.z) | (bf16rtne(v.w) << 16);
    unsigned int* Tw = (unsigned int*)(T + cl * 66 + u * 4);
    Tw[0] = p0;
    Tw[1] = p1;
  }
  __syncthreads();

  // ---- phase 2: LDS gather -> fragment-major 16B stores ----
  int x   = t >> 2;         // pixel 0..63
  int cq  = t & 3;
  int t16 = x >> 4, xl = x & 15;
  unsigned short* orow = op + (long)(b * H_ + y) * (W_ * C_);
#pragma unroll
  for (int g = 0; g < 4; g++) {
    int gg = (g + cq) & 3;              // bank-spread rotation
    int kgl = cq * 4 + gg;              // local k-granule 0..15
    int c0 = kgl * 8;                   // first local channel of this granule
    unsigned int wv[4];
#pragma unroll
    for (int k2 = 0; k2 < 4; k2++) {
      unsigned int lo = T[(c0 + 2 * k2) * 66 + x];
      unsigned int hi = T[(c0 + 2 * k2 + 1) * 66 + x];
      wv[k2] = lo | (hi << 16);
    }
    int kg = ch * 16 + kgl;             // global k-granule 0..31
    int ks = kg >> 2, qd = kg & 3;
    int G = ks * 256 + t16 * 64 + qd * 16 + xl;
    *(uint4*)(orow + (long)G * 8) = *(uint4*)wv;
  }
}

// ---------------------------------------------------------------------------
// async global -> LDS, 16B per lane (wave-uniform LDS base + lane*16)
// ---------------------------------------------------------------------------
__device__ __forceinline__ void gl_lds16(const void* g, void* l) {
  __builtin_amdgcn_global_load_lds(
      (const __attribute__((address_space(1))) void*)g,
      (__attribute__((address_space(3))) void*)l, 16, 0, 0);
}

// ---------------------------------------------------------------------------
// Kernel 2: correlation v14 — v13 + branch-free MFMA loop + depth-3 B prefetch.
// Ledger: v8/v10/v13 all pinned at 52.5us across 3 different memory plans ->
// L2-BW theory refuted. Invariants that remain: (1) depth-1 B prefetch
// (B likely L3-latency ~500cyc: output writes stream 11MB/XCD through the
// 4MB L2s, evicting B), (2) vector-guarded MFMAs: live[] is threadIdx-
// derived -> compiler emits v_cmp+saveexec+branch per guarded MFMA (~250
// insts/wave-iter since v5).
// v14 changes (inner loop only):
//   - MFMAs UNCONDITIONAL: dead tile-pairs have soff=-1 on all lanes, the
//     per-lane scatter guard already drops them. Hot loop = uniform,
//     branch-free. (+8 wasted MFMA/iter on half the waves ~= 40cyc, vs
//     killing the exec-juggling.)
//   - B prefetch depth 3: pb[8] static full-unroll SSA (compile-time
//     if(ks+3<8), no runtime branch); ks0-2 issued BEFORE the store phase.
//     ~24 extra VGPR, short live ranges; R4's sink pathology is gone (no
//     big loop-live arrays since A lives in LDS).
// Keeps: A in LDS (staged once, identity gl_lds16), XCD swizzle, dbuf slab,
// coalesced stores, lgkmcnt-only barrier.
// LDS = 32KB A + 10.9KB slab = 43.7KB -> 3 blocks/CU, grid fully resident.
// ---------------------------------------------------------------------------
__global__ __launch_bounds__(256, 3) void corr_kernel(
    const unsigned short* __restrict__ A2, const unsigned short* __restrict__ B2,
    float* __restrict__ out) {
  __shared__ unsigned short Alds[16384];    // 32KB A row, fragment-major
  __shared__ float slab[2][ND * 65];        // [buf][dxi][x], pad 65

  int bid = blockIdx.x;
  int blk = (bid & 7) * 96 + (bid >> 3);    // XCD swizzle, bijective (768=8*96)
  int y    = blk % H_;
  int b    = blk / H_;
  int t    = threadIdx.x;
  int lane = t & 63;
  int w    = t >> 6;
  int l15  = lane & 15;
  int quad = lane >> 4;
  int mh   = w & 1;
  int nh   = w >> 1;

  // contiguous valid-dyi range: y2 = y + 2*d - 20 in [0,H)
  int dlo = (y < 20) ? ((21 - y) >> 1) : 0;
  int dhi = (67 - y) >> 1; if (dhi > 20) dhi = 20;

  // ---- prologue: stage A row into LDS (identity copy, 32 x 1KB chunks) ----
  const unsigned short* rowA = A2 + (long)(b * H_ + y) * (W_ * C_);
  {
    const unsigned short* srcA = rowA + lane * 8;
#pragma unroll
    for (int j = 0; j < 8; j++) {
      int c = w * 8 + j;                    // chunk 0..31 (1KB each)
      gl_lds16(srcA + c * 512, &Alds[c * 512]);
    }
  }

  // ---- per-lane slab-scatter offsets (dyi-invariant): dxi*65 + xx, or -1 ----
  // dead tile-pairs (|tilediff|>2) give |dx|>=33>20 -> soff=-1 on ALL lanes,
  // so the scatter guard alone suffices; MFMAs can run unconditionally.
  int soff[2][2][4];
#pragma unroll
  for (int mtl = 0; mtl < 2; mtl++)
#pragma unroll
    for (int ntl = 0; ntl < 2; ntl++)
#pragma unroll
      for (int r = 0; r < 4; r++) {
        int xx = (mh * 2 + mtl) * 16 + quad * 4 + r;
        int xp = (nh * 2 + ntl) * 16 + l15;
        int dx = xp - xx;
        soff[mtl][ntl][r] =
            (dx >= -20 && dx <= 20 && !(dx & 1)) ? (((dx + 20) >> 1) * 65 + xx) : -1;
      }

  float* ob = out + (long)b * (ND * ND * HW) + y * W_;

  // ---- zero planes for out-of-range dyi (overlaps A-stage latency) ----
  for (int d = 0; d < dlo; d++) {
    float* od = ob + (long)d * (ND * HW);
    for (int i = t; i < ND * W_; i += 256) od[(i >> 6) * HW + (i & 63)] = 0.0f;
  }
  for (int d = dhi + 1; d < ND; d++) {
    float* od = ob + (long)d * (ND * HW);
    for (int i = t; i < ND * W_; i += 256) od[(i >> 6) * HW + (i & 63)] = 0.0f;
  }

  // ---- zero-init both slabs (contiguous) ----
  {
    float* s0 = &slab[0][0];
    for (int i = t; i < 2 * ND * 65; i += 256) s0[i] = 0.0f;
  }
  __syncthreads();   // full barrier: drains A-stage vmcnt + slab init

  // LDS byte bases for this wave's two A m-tiles (dyi-invariant)
  const unsigned short* aBase0 = &Alds[(mh * 2 + 0) * 512 + lane * 8];
  const unsigned short* aBase1 = &Alds[(mh * 2 + 1) * 512 + lane * 8];

  const unsigned short* browbase = B2 + (long)(b * H_) * (W_ * C_);
  int sp = 0;
  for (int d = dlo; d <= dhi; d++) {
    int y2 = y + 2 * d - 20;
    const unsigned short* rowB = browbase + (long)y2 * (W_ * C_);
    const unsigned short* rb0 = rowB + (nh * 2 + 0) * 512 + lane * 8;
    const unsigned short* rb1 = rowB + (nh * 2 + 1) * 512 + lane * 8;

    // ---- (0) issue B prefetch for ks=0..2 (6 loads); store phase covers ----
    bf16x8 pb0[8], pb1[8];
#pragma unroll
    for (int k = 0; k < 3; k++) {
      pb0[k] = *(const bf16x8*)(rb0 + k * 2048);
      pb1[k] = *(const bf16x8*)(rb1 + k * 2048);
    }

    // ---- (1) store previous dyi's slab (coalesced 256B/wave) + rezero ----
    if (d > dlo) {
      float* odp = ob + (long)(d - 1) * (ND * HW);
      float* sl = slab[sp ^ 1];
      for (int i = t; i < ND * W_; i += 256) {
        int dxi = i >> 6, x = i & 63;
        odp[dxi * HW + x] = sl[dxi * 65 + x];
        sl[dxi * 65 + x] = 0.0f;
      }
    }

    // ---- (2) MFMA loop: branch-free, depth-3 B pipeline, depth-1 A ----
    f32x4 acc[2][2];
#pragma unroll
    for (int mtl = 0; mtl < 2; mtl++)
#pragma unroll
      for (int ntl = 0; ntl < 2; ntl++) acc[mtl][ntl] = (f32x4){0.f, 0.f, 0.f, 0.f};

    bf16x8 a0 = *(const bf16x8*)(aBase0);
    bf16x8 a1 = *(const bf16x8*)(aBase1);

#pragma unroll
    for (int ks = 0; ks < 8; ks++) {
      if (ks + 3 < 8) {                       // compile-time: no runtime branch
        pb0[ks + 3] = *(const bf16x8*)(rb0 + (ks + 3) * 2048);
        pb1[ks + 3] = *(const bf16x8*)(rb1 + (ks + 3) * 2048);
      }
      int ksn = (ks < 7) ? ks + 1 : 0;        // clamp: harmless extra LDS read
      bf16x8 an0 = *(const bf16x8*)(aBase0 + ksn * 2048);
      bf16x8 an1 = *(const bf16x8*)(aBase1 + ksn * 2048);
      acc[0][0] = __builtin_amdgcn_mfma_f32_16x16x32_bf16(a0, pb0[ks], acc[0][0], 0, 0, 0);
      acc[0][1] = __builtin_amdgcn_mfma_f32_16x16x32_bf16(a0, pb1[ks], acc[0][1], 0, 0, 0);
      acc[1][0] = __builtin_amdgcn_mfma_f32_16x16x32_bf16(a1, pb0[ks], acc[1][0], 0, 0, 0);
      acc[1][1] = __builtin_amdgcn_mfma_f32_16x16x32_bf16(a1, pb1[ks], acc[1][1], 0, 0, 0);
      a0 = an0; a1 = an1;                     // unconditional rotation
    }

    // ---- (3) band-extract scatter into slab[sp] (per-lane guard only) ----
#pragma unroll
    for (int mtl = 0; mtl < 2; mtl++)
#pragma unroll
      for (int ntl = 0; ntl < 2; ntl++)
#pragma unroll
        for (int r = 0; r < 4; r++) {
          int so = soff[mtl][ntl][r];
          if (so >= 0) slab[sp][so] = acc[mtl][ntl][r] * (1.0f / 256.0f);
        }

    // ---- (4) relaxed barrier: LDS drained, NO vmcnt drain ----
    asm volatile("s_waitcnt lgkmcnt(0)" ::: "memory");
    __builtin_amdgcn_s_barrier();
    __builtin_amdgcn_sched_barrier(0);
    sp ^= 1;
  }

  // ---- epilogue: store last dyi's slab ----
  {
    float* odp = ob + (long)dhi * (ND * HW);
    float* sl = slab[sp ^ 1];
    for (int i = t; i < ND * W_; i += 256) {
      int dxi = i >> 6, x = i & 63;
      odp[dxi * HW + x] = sl[dxi * 65 + x];
    }
  }
}

// ---------------------------------------------------------------------------
extern "C" void kernel_launch(void* const* d_in, const int* in_sizes, int n_in,
                              void* d_out, int out_size, void* d_ws, size_t ws_size,
                              hipStream_t stream) {
  (void)in_sizes; (void)n_in; (void)out_size; (void)ws_size;
  const float* in1 = (const float*)d_in[0];
  const float* in2 = (const float*)d_in[1];
  float* out = (float*)d_out;

  unsigned short* o1 = (unsigned short*)d_ws;                    // bf16 frag-major
  unsigned short* o2 = o1 + (size_t)B_ * H_ * W_ * C_;           // bf16 frag-major

  transpose_cvt<<<4 * B_ * H_, 256, 0, stream>>>(in1, in2, o1, o2);
  corr_kernel<<<B_ * H_, 256, 0, stream>>>(o1, o2, out);
}